// Round 13
// baseline (2557.933 us; speedup 1.0000x reference)
//
#include <hip/hip_runtime.h>
#include <hip/hip_bf16.h>

// FF_attention_module: sLSTM scan (T=128) + attention epilogue.
// Round 13: exact R9 sync skeleton (proven 1503us scan), compute switched
// to v_mfma_f32_32x32x16_bf16 with 256 threads / 4 waves (2rw x 2cw, each
// wave 32 rows x 96 gate-cols + one 32x32 j-tile). Same LDS layouts, same
// staging, same exchange protocol, same prep kernels as R9.

namespace {
constexpr int B_  = 1024;
constexpr int T_  = 128;
constexpr int D_  = 16;
constexpr int DN_ = 1024;
constexpr int NIV = 8;       // 8 intervals of K=128 (pure h, 1024 total)

constexpr size_t INPBUF   = (size_t)128 * 1024 * 8 * 2;      // 2,097,152
constexpr size_t OFF_INP0 = 0;
constexpr size_t OFF_INP1 = INPBUF;
constexpr size_t OFF_FLAGS= 2 * INPBUF;                      // 4,194,304
constexpr size_t OFF_SEH  = OFF_FLAGS + (size_t)16 * 128 * 4;
constexpr size_t OFF_SE   = OFF_SEH + (size_t)B_ * DN_ * 4;
constexpr size_t OFF_HT   = OFF_SE  + (size_t)B_ * D_ * 4;
constexpr size_t OFF_W2   = OFF_HT  + (size_t)B_ * DN_ * 4;
constexpr size_t OFF_WJ2  = OFF_W2  + (size_t)16 * 8 * 24576 * 2;
constexpr size_t OFF_WX2  = OFF_WJ2 + (size_t)16 * 4096 * 2;
constexpr size_t ZERO_BYTES = OFF_SEH;   // zero inp0+inp1+flags only
}

typedef __attribute__((ext_vector_type(8)))  __bf16 bf8;
typedef __attribute__((ext_vector_type(16))) float  f16v;
typedef __attribute__((ext_vector_type(4)))  unsigned int u32x4;

__device__ __forceinline__ unsigned short f2bf(float v) {
    unsigned int u = __float_as_uint(v);
    unsigned int r = u + 0x7FFFu + ((u >> 16) & 1u);   // RNE
    return (unsigned short)(r >> 16);
}
__device__ __forceinline__ float rcpf(float x) { return __builtin_amdgcn_rcpf(x); }
__device__ __forceinline__ float tanhf_fast(float x) {
    x = fminf(fmaxf(x, -15.0f), 15.0f);
    float e = __expf(2.0f * x);
    return (e - 1.0f) * rcpf(e + 1.0f);
}
__device__ __forceinline__ float sigmoidf_fast(float x) {
    return rcpf(1.0f + __expf(-x));
}
__device__ __forceinline__ void gl16(const unsigned short* g, unsigned short* l) {
    __builtin_amdgcn_global_load_lds(
        (const __attribute__((address_space(1))) unsigned int*)g,
        (__attribute__((address_space(3))) unsigned int*)l, 16, 0, 0);
}
// coherence-point act read (aux 0x11 = sc0|sc1) — R9-proven
__device__ __forceinline__ void gl16c(const unsigned short* g, unsigned short* l) {
    __builtin_amdgcn_global_load_lds(
        (const __attribute__((address_space(1))) unsigned int*)g,
        (__attribute__((address_space(3))) unsigned int*)l, 16, 0, 17);
}
// coherence-point 16B store (sc0 sc1)
__device__ __forceinline__ void st16c(void* gaddr, u32x4 v) {
    unsigned long long a = (unsigned long long)gaddr;
    asm volatile("global_store_dwordx4 %0, %1, off sc0 sc1"
                 :: "v"(a), "v"(v) : "memory");
}
__device__ __forceinline__ void drain_vmem() {
    asm volatile("s_waitcnt vmcnt(0)" ::: "memory");
}

// ---- prep kernels: identical to R9 ----
// W2 flat (shorts): (((d*8 + iv)*16 + kg)*192 + col)*8 + e
// original k = 16 + iv*128 + kg*8 + e ; col = gate*64 + c
__global__ __launch_bounds__(256)
void prep_w2(const float* __restrict__ Wi, const float* __restrict__ Wf,
             const float* __restrict__ Wo, unsigned short* __restrict__ W2)
{
    int idx = blockIdx.x * 256 + threadIdx.x;
    if (idx >= 16 * 8 * 16 * 192 * 8) return;
    int e   = idx & 7;
    int t1  = idx >> 3;
    int col = t1 % 192;
    int t2  = t1 / 192;
    int kg  = t2 & 15;
    int t3  = t2 >> 4;
    int iv  = t3 & 7;
    int d   = t3 >> 3;
    int k   = 16 + iv * 128 + kg * 8 + e;
    int gate = col >> 6, c = col & 63;
    const float* W = (gate == 0) ? Wi : (gate == 1) ? Wf : Wo;
    W2[idx] = f2bf(W[(size_t)(d * 64 + c) * 1040 + k]);
}

// Wj2: ((d*8 + kb)*64 + m)*8 + e ; Wx2: ((d*4 + kg)*192 + col)*8 + e
__global__ __launch_bounds__(256)
void prep_misc(const float* __restrict__ Wj,
               const float* __restrict__ Wi, const float* __restrict__ Wf,
               const float* __restrict__ Wo,
               unsigned short* __restrict__ Wj2, unsigned short* __restrict__ Wx2)
{
    int idx = blockIdx.x * 256 + threadIdx.x;
    if (idx < 65536) {
        int e  = idx & 7;
        int m  = (idx >> 3) & 63;
        int kb = (idx >> 9) & 7;
        int d  = idx >> 12;
        int n  = kb * 8 + e;
        Wj2[idx] = f2bf(Wj[((size_t)d * 64 + n) * 64 + m]);
    } else if (idx < 65536 + 98304) {
        int i2  = idx - 65536;
        int e   = i2 & 7;
        int t1  = i2 >> 3;
        int col = t1 % 192;
        int t2  = t1 / 192;
        int kg  = t2 & 3;
        int d   = t2 >> 2;
        int k   = kg * 8 + e;
        int gate = col >> 6, c = col & 63;
        float v = 0.0f;
        if (k < 16) {
            const float* W = (gate == 0) ? Wi : (gate == 1) ? Wf : Wo;
            v = W[(size_t)(d * 64 + c) * 1040 + k];
        }
        Wx2[i2] = f2bf(v);
    }
}

// ---- persistent scan: 1D grid 256, 256 threads = 4 waves ----
// XCD-aware decode: xcd = id%8 hosts d in {2*xcd, 2*xcd+1} for all bt.
// Wave (rw, cw): rows rbase=32*rw..+32, dn cols dnb=32*cw..+32 (x3 gates).
__global__ __launch_bounds__(256, 1)
void scan_kernel(
    const float* __restrict__ x,
    const float* __restrict__ U_j, const float* __restrict__ b_j,
    const float* __restrict__ Wi_b, const float* __restrict__ Wf_b,
    const float* __restrict__ Wo_b,
    const float* __restrict__ F_an, const float* __restrict__ F_anb,
    const unsigned short* __restrict__ W2, const unsigned short* __restrict__ Wj2,
    const unsigned short* __restrict__ Wx2,
    unsigned short* __restrict__ inp0, unsigned short* __restrict__ inp1,
    int* __restrict__ flags,
    float* __restrict__ Seh, float* __restrict__ Se, float* __restrict__ hT)
{
    const int id  = blockIdx.x;
    const int d   = (id & 7) * 2 + ((id >> 3) & 1);
    const int bt  = id >> 4;
    const int b0  = bt * 64;
    const int tid = threadIdx.x;
    const int wv  = tid >> 6;        // 0..3
    const int cw  = wv & 1;
    const int rw  = wv >> 1;
    const int ln  = tid & 63;
    const int lc  = ln & 31;         // 32x32 fragment row/col index
    const int l5  = ln >> 5;         // k-octet select within K=16
    const int dnb   = cw * 32;
    const int rbase = rw * 32;
    const int dn    = dnb + lc;      // this lane's dn column

    // LDS map identical to R9
    __shared__ __align__(16) unsigned char smem[156416];
    unsigned short* a_sb0 = (unsigned short*)smem;             // 16 KB
    unsigned short* a_sb1 = (unsigned short*)(smem + 16384);   // 16 KB
    unsigned short* w_sb  = (unsigned short*)(smem + 32768);   // 2 x 48 KB
    unsigned short* wj_s  = (unsigned short*)(smem + 131072);  // 8 KB
    unsigned short* wx_s  = (unsigned short*)(smem + 139264);  // 12 KB
    unsigned short* xa_s  = (unsigned short*)(smem + 151552);  // [64][32]
    float* xd_s = (float*)(smem + 155648);
    float* fa_s = xd_s + 64;
    float* e_s  = xd_s + 128;
    typedef float (*hnrow_t)[66];
    hnrow_t hn_s = (hnrow_t)smem;    // 64x66 f32 overlay on a_s

    const float uc   = U_j[d * 64 + dn];
    const float bc   = b_j[d * 64 + dn];
    const float bi_c = Wi_b[d * 64 + dn];
    const float bf_c = Wf_b[d * 64 + dn];
    const float bo_c = Wo_b[d * 64 + dn];
    const float fanb = F_anb[d];
    if (tid < 64) fa_s[tid] = F_an[d * 64 + tid];
    // one-time stages: Wj (8 granules, 2/wave), Wx (12 granules, 3/wave)
    #pragma unroll
    for (int i = 0; i < 2; ++i) {
        int g = wv * 2 + i;
        gl16(Wj2 + (size_t)d * 4096 + (size_t)(g * 64 + ln) * 8, wj_s + g * 512);
    }
    #pragma unroll
    for (int i = 0; i < 3; ++i) {
        int g = wv * 3 + i;
        gl16(Wx2 + (size_t)d * 6144 + (size_t)(g * 64 + ln) * 8, wx_s + g * 512);
    }
    {   // zero-pad xa (all 256 threads cover 64x32 shorts: 8 shorts each)
        *(ushort4*)&xa_s[tid * 8]     = make_ushort4(0, 0, 0, 0);
        *(ushort4*)&xa_s[tid * 8 + 4] = make_ushort4(0, 0, 0, 0);
    }
    const unsigned short* W2d = W2 + (size_t)d * (8 * 24576);
    const int jiv = d >> 1;          // interval holding own h d-slice
    const int jgb = (d & 1) * 8;     // octet base within that interval

    float c_r[16]   = {};
    float seh_r[16] = {};
    float se_r = 0.0f;
    const f16v fz16 = {0.f,0.f,0.f,0.f, 0.f,0.f,0.f,0.f,
                       0.f,0.f,0.f,0.f, 0.f,0.f,0.f,0.f};

    for (int t = 0; t < T_; ++t) {
        const unsigned short* cur = (t & 1) ? inp1 : inp0;
        unsigned short*       nxt = (t & 1) ? inp0 : inp1;

        // ---- pre-loop: x staging + weight interval 0 (flag-independent) ----
        if (tid < 64) xd_s[tid] = x[(size_t)(b0 + tid) * 2048 + t * 16 + d];
        {
            int b = tid >> 2, q = tid & 3;
            float4 xv = *(const float4*)&x[(size_t)(b0 + b) * 2048 + t * 16 + q * 4];
            *(ushort4*)&xa_s[b * 32 + q * 4] =
                make_ushort4(f2bf(xv.x), f2bf(xv.y), f2bf(xv.z), f2bf(xv.w));
        }
        #pragma unroll
        for (int i = 0; i < 12; ++i) {
            int gw = wv * 12 + i;
            gl16(W2d + (size_t)(gw * 64 + ln) * 8, w_sb + gw * 512);
        }
        if (t > 0) {
            if (tid == 0) {
                while (__hip_atomic_load(&flags[bt * 128 + t], __ATOMIC_RELAXED,
                                         __HIP_MEMORY_SCOPE_AGENT) < 16)
                    __builtin_amdgcn_s_sleep(1);
            }
        }
        __syncthreads();   // flag visible; xa/w0 staged

        // issue act interval 0 (coherent), 4 granules/wave
        #pragma unroll
        for (int i = 0; i < 4; ++i) {
            int ga = wv * 4 + i;
            gl16c(cur + ((size_t)ga * 1024 + b0 + ln) * 8, a_sb0 + ga * 512);
        }
        // x-chunk MFMA (K=16): initialize accumulators
        f16v acc[3];
        {
            bf8 xaf = *(const bf8*)&xa_s[(rbase + lc) * 32 + l5 * 8];
            #pragma unroll
            for (int g = 0; g < 3; ++g) {
                bf8 wxf = *(const bf8*)&wx_s[((l5) * 192 + g * 64 + dnb + lc) * 8];
                acc[g] = __builtin_amdgcn_mfma_f32_32x32x16_bf16(
                    xaf, wxf, fz16, 0, 0, 0);
            }
        }
        f16v jacc = fz16;
        __syncthreads();   // a0 drained

        // ---- 8 intervals of K=128, double-buffered (R9 engine) ----
        int buf = 0;
        for (int iv = 0; iv < NIV; ++iv) {
            const unsigned short* a_cur = buf ? a_sb1 : a_sb0;
            const unsigned short* w_cur = w_sb + buf * 24576;
            if (iv < NIV - 1) {
                unsigned short* a_nxt = buf ? a_sb0 : a_sb1;
                unsigned short* w_nxt = w_sb + (buf ^ 1) * 24576;
                #pragma unroll
                for (int i = 0; i < 4; ++i) {   // acts first (longer latency)
                    int ga = wv * 4 + i;
                    gl16c(cur + ((size_t)((iv + 1) * 16 + ga) * 1024 + b0 + ln) * 8,
                          a_nxt + ga * 512);
                }
                const unsigned short* wsrc = W2d + (size_t)(iv + 1) * 24576;
                #pragma unroll
                for (int i = 0; i < 12; ++i) {
                    int gw = wv * 12 + i;
                    gl16(wsrc + (size_t)(gw * 64 + ln) * 8, w_nxt + gw * 512);
                }
            }
            #pragma unroll
            for (int ks = 0; ks < 8; ++ks) {
                int koct = ks * 2 + l5;
                bf8 af = *(const bf8*)&a_cur[koct * 512 + (rbase + lc) * 8];
                #pragma unroll
                for (int g = 0; g < 3; ++g) {
                    bf8 bw = *(const bf8*)&w_cur[(koct * 192 + g * 64 + dnb + lc) * 8];
                    acc[g] = __builtin_amdgcn_mfma_f32_32x32x16_bf16(
                        af, bw, acc[g], 0, 0, 0);
                }
            }
            if (iv == jiv) {   // j = h_d @ W_j[d], one 32x32 tile per wave
                #pragma unroll
                for (int ks2 = 0; ks2 < 4; ++ks2) {
                    bf8 ah = *(const bf8*)&a_cur[(jgb + ks2 * 2 + l5) * 512
                                                 + (rbase + lc) * 8];
                    bf8 bw = *(const bf8*)&wj_s[((ks2 * 2 + l5) * 64 + dnb + lc) * 8];
                    jacc = __builtin_amdgcn_mfma_f32_32x32x16_bf16(
                        ah, bw, jacc, 0, 0, 0);
                }
            }
            __syncthreads();
            buf ^= 1;
        }

        // ---- gates + c/h update (32x32 C layout: col=lc, row below) ----
        #pragma unroll
        for (int r = 0; r < 16; ++r) {
            int row = rbase + (r & 3) + 8 * (r >> 2) + 4 * l5;
            float jr  = tanhf_fast(jacc[r] + xd_s[row] * uc + bc);
            float iv_ = sigmoidf_fast(acc[0][r] + bi_c);
            float fv  = sigmoidf_fast(acc[1][r] + bf_c);
            float ov  = sigmoidf_fast(acc[2][r] + bo_c);
            float cn  = c_r[r] * fv + iv_ * jr;
            c_r[r] = cn;
            float hn = ov * tanhf_fast(cn);
            hn_s[row][dn] = hn;
        }
        __syncthreads();

        // ---- publish h_{t+1} via LLC stores; post flag ----
        if (t < T_ - 1) {
            #pragma unroll
            for (int i = 0; i < 2; ++i) {
                int gw = wv * 2 + i;
                __align__(16) unsigned short pk[8];
                #pragma unroll
                for (int e = 0; e < 8; ++e) pk[e] = f2bf(hn_s[ln][gw * 8 + e]);
                st16c(nxt + ((size_t)(d * 8 + gw) * 1024 + b0 + ln) * 8,
                      *(const u32x4*)pk);
            }
            drain_vmem();            // stores reached the LLC
            __syncthreads();         // all waves drained
            if (tid == 0)
                atomicAdd(&flags[bt * 128 + (t + 1)], 1);
        }

        // ---- online alpha accumulation (256 threads) ----
        {
            int b = tid >> 2, q = tid & 3;
            float s = 0.0f;
            #pragma unroll
            for (int i2 = 0; i2 < 16; ++i2)
                s += hn_s[b][q * 16 + i2] * fa_s[q * 16 + i2];
            s += __shfl_xor(s, 1);
            s += __shfl_xor(s, 2);
            float e = __expf(tanhf_fast(s + fanb));
            if (q == 0) { e_s[b] = e; se_r += e; }
        }
        __syncthreads();
        #pragma unroll
        for (int r = 0; r < 16; ++r) {
            int row = rbase + (r & 3) + 8 * (r >> 2) + 4 * l5;
            seh_r[r] += e_s[row] * hn_s[row][dn];
        }
        __syncthreads();   // hn_s reads done before next step overwrites a_s
    }

    // ---- final writes: hT (t=127 h from hn_s), Se, Seh ----
    {
        int b = tid >> 2, q = tid & 3;
        #pragma unroll
        for (int i2 = 0; i2 < 4; ++i2) {
            float4 v;
            v.x = hn_s[b][q * 16 + i2 * 4 + 0];
            v.y = hn_s[b][q * 16 + i2 * 4 + 1];
            v.z = hn_s[b][q * 16 + i2 * 4 + 2];
            v.w = hn_s[b][q * 16 + i2 * 4 + 3];
            *(float4*)&hT[(size_t)(b0 + b) * DN_ + d * 64 + q * 16 + i2 * 4] = v;
        }
        if (q == 0) Se[(size_t)(b0 + b) * D_ + d] = se_r;
    }
    #pragma unroll
    for (int r = 0; r < 16; ++r) {
        int row = rbase + (r & 3) + 8 * (r >> 2) + 4 * l5;
        Seh[((size_t)(b0 + row) * D_ + d) * 64 + dn] = seh_r[r];
    }
}

// ---- epilogue ----
__global__ __launch_bounds__(64)
void final_kernel(const float* __restrict__ hT,
                  const float* __restrict__ Se, const float* __restrict__ Seh,
                  const float* __restrict__ F_bw, const float* __restrict__ F_bb,
                  const float* __restrict__ Phi_w, const float* __restrict__ Phi_b,
                  float* __restrict__ out)
{
    int b = blockIdx.x;
    int tid = threadIdx.x;
    int d = tid >> 2, q = tid & 3;
    float se_inv = 1.0f / Se[(size_t)b * D_ + d];
    float mu = 0.0f, be = 0.0f;
    #pragma unroll
    for (int i = 0; i < 32; ++i) {
        int k = q * 32 + i;
        float hg = (k < 64) ? Seh[((size_t)b * D_ + d) * 64 + k] * se_inv
                            : hT[(size_t)b * DN_ + d * 64 + (k - 64)];
        mu += hg * Phi_w[k];
        be += hg * F_bw[k];
    }
    mu += __shfl_xor(mu, 1); mu += __shfl_xor(mu, 2);
    be += __shfl_xor(be, 1); be += __shfl_xor(be, 2);
    float mud = mu + Phi_b[0];
    float br  = __expf(tanhf_fast(be + F_bb[0]));
    float num = br * mud, den = br;
    #pragma unroll
    for (int off = 4; off < 64; off <<= 1) {
        num += __shfl_xor(num, off);
        den += __shfl_xor(den, off);
    }
    if (tid == 0) out[b] = num / den;
}

extern "C" void kernel_launch(void* const* d_in, const int* in_sizes, int n_in,
                              void* d_out, int out_size, void* d_ws, size_t ws_size,
                              hipStream_t stream)
{
    (void)in_sizes; (void)n_in; (void)out_size; (void)ws_size;
    const float* x     = (const float*)d_in[0];
    const float* U_j   = (const float*)d_in[1];
    const float* W_j   = (const float*)d_in[2];
    const float* b_j   = (const float*)d_in[3];
    const float* Wi_w  = (const float*)d_in[4];
    const float* Wi_b  = (const float*)d_in[5];
    const float* Wf_w  = (const float*)d_in[6];
    const float* Wf_b  = (const float*)d_in[7];
    const float* Wo_w  = (const float*)d_in[8];
    const float* Wo_b  = (const float*)d_in[9];
    const float* F_an  = (const float*)d_in[10];
    const float* F_anb = (const float*)d_in[11];
    const float* F_bw  = (const float*)d_in[12];
    const float* F_bb  = (const float*)d_in[13];
    const float* Phi_w = (const float*)d_in[14];
    const float* Phi_b = (const float*)d_in[15];
    float* out = (float*)d_out;

    char* ws = (char*)d_ws;
    unsigned short* inp0 = (unsigned short*)(ws + OFF_INP0);
    unsigned short* inp1 = (unsigned short*)(ws + OFF_INP1);
    int*   flags = (int*)(ws + OFF_FLAGS);
    float* Seh   = (float*)(ws + OFF_SEH);
    float* Se    = (float*)(ws + OFF_SE);
    float* hT    = (float*)(ws + OFF_HT);
    unsigned short* W2  = (unsigned short*)(ws + OFF_W2);
    unsigned short* Wj2 = (unsigned short*)(ws + OFF_WJ2);
    unsigned short* Wx2 = (unsigned short*)(ws + OFF_WX2);

    (void)hipMemsetAsync(d_ws, 0, ZERO_BYTES, stream);
    prep_w2<<<dim3(12288), dim3(256), 0, stream>>>(Wi_w, Wf_w, Wo_w, W2);
    prep_misc<<<dim3(640), dim3(256), 0, stream>>>(W_j, Wi_w, Wf_w, Wo_w, Wj2, Wx2);

    // 1D grid, XCD-aware decode inside the kernel; 1 block/CU (153KB LDS)
    scan_kernel<<<dim3(256), dim3(256), 0, stream>>>(
        x, U_j, b_j, Wi_b, Wf_b, Wo_b, F_an, F_anb,
        W2, Wj2, Wx2, inp0, inp1, flags, Seh, Se, hT);

    final_kernel<<<dim3(B_), dim3(64), 0, stream>>>(hT, Se, Seh, F_bw, F_bb,
                                                    Phi_w, Phi_b, out);
}

// Round 14
// 1370.758 us; speedup vs baseline: 1.8661x; 1.8661x over previous
//
#include <hip/hip_runtime.h>
#include <hip/hip_bf16.h>

// FF_attention_module: sLSTM scan (T=128) + attention epilogue.
// Round 14: revert to Round 9 (best: 1370us) byte-identical engine.
// Only delta: memset covers inp0+flags only (inp1 is write-before-read).
// R9 = XCD-aware 1D grid, 8 uniform K=128 h-intervals, x-part via
// resident Wx MFMA accumulator init, sc0|sc1 LLC exchange, group flags.

namespace {
constexpr int B_  = 1024;
constexpr int T_  = 128;
constexpr int D_  = 16;
constexpr int DN_ = 1024;
constexpr int NIV = 8;       // 8 intervals of K=128 (pure h, 1024 total)

constexpr size_t INPBUF   = (size_t)128 * 1024 * 8 * 2;      // 2,097,152
constexpr size_t OFF_INP0 = 0;
constexpr size_t OFF_INP1 = INPBUF;
constexpr size_t OFF_FLAGS= 2 * INPBUF;                      // 4,194,304
constexpr size_t FLAGS_BYTES = (size_t)16 * 128 * 4;         // 8,192
constexpr size_t OFF_SEH  = OFF_FLAGS + FLAGS_BYTES;
constexpr size_t OFF_SE   = OFF_SEH + (size_t)B_ * DN_ * 4;
constexpr size_t OFF_HT   = OFF_SE  + (size_t)B_ * D_ * 4;
constexpr size_t OFF_W2   = OFF_HT  + (size_t)B_ * DN_ * 4;
constexpr size_t OFF_WJ2  = OFF_W2  + (size_t)16 * 8 * 24576 * 2;
constexpr size_t OFF_WX2  = OFF_WJ2 + (size_t)16 * 4096 * 2;
}

typedef __attribute__((ext_vector_type(8))) __bf16 bf8;
typedef __attribute__((ext_vector_type(4))) float  f4;
typedef __attribute__((ext_vector_type(4))) unsigned int u32x4;

__device__ __forceinline__ unsigned short f2bf(float v) {
    unsigned int u = __float_as_uint(v);
    unsigned int r = u + 0x7FFFu + ((u >> 16) & 1u);   // RNE
    return (unsigned short)(r >> 16);
}
__device__ __forceinline__ float rcpf(float x) { return __builtin_amdgcn_rcpf(x); }
__device__ __forceinline__ float tanhf_fast(float x) {
    x = fminf(fmaxf(x, -15.0f), 15.0f);
    float e = __expf(2.0f * x);
    return (e - 1.0f) * rcpf(e + 1.0f);
}
__device__ __forceinline__ float sigmoidf_fast(float x) {
    return rcpf(1.0f + __expf(-x));
}
__device__ __forceinline__ void gl16(const unsigned short* g, unsigned short* l) {
    __builtin_amdgcn_global_load_lds(
        (const __attribute__((address_space(1))) unsigned int*)g,
        (__attribute__((address_space(3))) unsigned int*)l, 16, 0, 0);
}
// coherence-point read (aux 0x11 = sc0|sc1)
__device__ __forceinline__ void gl16c(const unsigned short* g, unsigned short* l) {
    __builtin_amdgcn_global_load_lds(
        (const __attribute__((address_space(1))) unsigned int*)g,
        (__attribute__((address_space(3))) unsigned int*)l, 16, 0, 17);
}
// coherence-point 16B store (sc0 sc1)
__device__ __forceinline__ void st16c(void* gaddr, u32x4 v) {
    unsigned long long a = (unsigned long long)gaddr;
    asm volatile("global_store_dwordx4 %0, %1, off sc0 sc1"
                 :: "v"(a), "v"(v) : "memory");
}
__device__ __forceinline__ void drain_vmem() {
    asm volatile("s_waitcnt vmcnt(0)" ::: "memory");
}

// ---- prep: gate weights fp32 -> bf16, 8 uniform K=128 h-intervals ----
// W2 flat (shorts): (((d*8 + iv)*16 + kg)*192 + col)*8 + e
// original k = 16 + iv*128 + kg*8 + e ; col = gate*64 + c
__global__ __launch_bounds__(256)
void prep_w2(const float* __restrict__ Wi, const float* __restrict__ Wf,
             const float* __restrict__ Wo, unsigned short* __restrict__ W2)
{
    int idx = blockIdx.x * 256 + threadIdx.x;
    if (idx >= 16 * 8 * 16 * 192 * 8) return;
    int e   = idx & 7;
    int t1  = idx >> 3;
    int col = t1 % 192;
    int t2  = t1 / 192;
    int kg  = t2 & 15;
    int t3  = t2 >> 4;
    int iv  = t3 & 7;
    int d   = t3 >> 3;
    int k   = 16 + iv * 128 + kg * 8 + e;
    int gate = col >> 6, c = col & 63;
    const float* W = (gate == 0) ? Wi : (gate == 1) ? Wf : Wo;
    W2[idx] = f2bf(W[(size_t)(d * 64 + c) * 1040 + k]);
}

// Wj2: ((d*8 + kb)*64 + m)*8 + e  (= W_j[d][n=kb*8+e][m])
// Wx2: ((d*4 + kg)*192 + col)*8 + e  (= Wgate[d*64+c][k=kg*8+e], 0 for k>=16)
__global__ __launch_bounds__(256)
void prep_misc(const float* __restrict__ Wj,
               const float* __restrict__ Wi, const float* __restrict__ Wf,
               const float* __restrict__ Wo,
               unsigned short* __restrict__ Wj2, unsigned short* __restrict__ Wx2)
{
    int idx = blockIdx.x * 256 + threadIdx.x;
    if (idx < 65536) {
        int e  = idx & 7;
        int m  = (idx >> 3) & 63;
        int kb = (idx >> 9) & 7;
        int d  = idx >> 12;
        int n  = kb * 8 + e;
        Wj2[idx] = f2bf(Wj[((size_t)d * 64 + n) * 64 + m]);
    } else if (idx < 65536 + 98304) {
        int i2  = idx - 65536;
        int e   = i2 & 7;
        int t1  = i2 >> 3;
        int col = t1 % 192;
        int t2  = t1 / 192;
        int kg  = t2 & 3;
        int d   = t2 >> 2;
        int k   = kg * 8 + e;
        int gate = col >> 6, c = col & 63;
        float v = 0.0f;
        if (k < 16) {
            const float* W = (gate == 0) ? Wi : (gate == 1) ? Wf : Wo;
            v = W[(size_t)(d * 64 + c) * 1040 + k];
        }
        Wx2[i2] = f2bf(v);
    }
}

// ---- persistent scan: 1D grid 256, 512 threads = 8 waves ----
// XCD-aware decode: xcd = id%8 hosts d in {2*xcd, 2*xcd+1} for all bt
// -> per-XCD weight working set = 786 KB (L2-resident).
__global__ __launch_bounds__(512, 1)
void scan_kernel(
    const float* __restrict__ x,
    const float* __restrict__ U_j, const float* __restrict__ b_j,
    const float* __restrict__ Wi_b, const float* __restrict__ Wf_b,
    const float* __restrict__ Wo_b,
    const float* __restrict__ F_an, const float* __restrict__ F_anb,
    const unsigned short* __restrict__ W2, const unsigned short* __restrict__ Wj2,
    const unsigned short* __restrict__ Wx2,
    unsigned short* __restrict__ inp0, unsigned short* __restrict__ inp1,
    int* __restrict__ flags,
    float* __restrict__ Seh, float* __restrict__ Se, float* __restrict__ hT)
{
    const int id  = blockIdx.x;
    const int d   = (id & 7) * 2 + ((id >> 3) & 1);
    const int bt  = id >> 4;
    const int b0  = bt * 64;
    const int tid = threadIdx.x;
    const int wv  = tid >> 6;        // 0..7
    const int cw  = wv & 3;
    const int rw  = wv >> 2;
    const int ln  = tid & 63;
    const int lr  = ln & 15;
    const int lg  = ln >> 4;
    const int coln  = cw * 16 + lr;
    const int rbase = rw * 32;

    // LDS: a 2x16K | w 2x48K | wj 8K | wx 12K | xa 4K | xd/fa/e 768B
    __shared__ __align__(16) unsigned char smem[156416];
    unsigned short* a_sb0 = (unsigned short*)smem;
    unsigned short* a_sb1 = (unsigned short*)(smem + 16384);
    unsigned short* w_sb  = (unsigned short*)(smem + 32768);   // 2 x 24576
    unsigned short* wj_s  = (unsigned short*)(smem + 131072);  // 4096
    unsigned short* wx_s  = (unsigned short*)(smem + 139264);  // 6144
    unsigned short* xa_s  = (unsigned short*)(smem + 151552);  // [64][32]
    float* xd_s = (float*)(smem + 155648);
    float* fa_s = xd_s + 64;
    float* e_s  = xd_s + 128;
    typedef float (*hnrow_t)[66];
    hnrow_t hn_s = (hnrow_t)smem;    // 64x66 f32 overlay on a_s

    const float uc   = U_j[d * 64 + coln];
    const float bc   = b_j[d * 64 + coln];
    const float bi_c = Wi_b[d * 64 + coln];
    const float bf_c = Wf_b[d * 64 + coln];
    const float bo_c = Wo_b[d * 64 + coln];
    const float fanb = F_anb[d];
    if (tid < 64) fa_s[tid] = F_an[d * 64 + tid];
    // one-time stages: Wj (8 granules), Wx (12 granules), xa zero-pad
    gl16(Wj2 + (size_t)d * 4096 + (size_t)(wv * 64 + ln) * 8, wj_s + wv * 512);
    #pragma unroll
    for (int i = 0; i < 2; ++i) {
        int g = wv + i * 8;
        if (g < 12)
            gl16(Wx2 + (size_t)d * 6144 + (size_t)(g * 64 + ln) * 8, wx_s + g * 512);
    }
    *(ushort4*)&xa_s[tid * 4] = make_ushort4(0, 0, 0, 0);
    const unsigned short* W2d = W2 + (size_t)d * (8 * 24576);
    const int jiv = d >> 1;          // interval holding own h d-slice
    const int jgb = (d & 1) * 8;     // granule base within that interval

    float c_r[2][4]   = {};
    float seh_r[2][4] = {};
    float se_r = 0.0f;
    const f4 fz = {0.f, 0.f, 0.f, 0.f};

    for (int t = 0; t < T_; ++t) {
        const unsigned short* cur = (t & 1) ? inp1 : inp0;
        unsigned short*       nxt = (t & 1) ? inp0 : inp1;

        // ---- pre-loop: x staging + weight interval 0 (flag-independent) ----
        if (tid < 64) xd_s[tid] = x[(size_t)(b0 + tid) * 2048 + t * 16 + d];
        if (tid < 256) {
            int b = tid >> 2, q = tid & 3;
            float4 xv = *(const float4*)&x[(size_t)(b0 + b) * 2048 + t * 16 + q * 4];
            *(ushort4*)&xa_s[b * 32 + q * 4] =
                make_ushort4(f2bf(xv.x), f2bf(xv.y), f2bf(xv.z), f2bf(xv.w));
        }
        #pragma unroll
        for (int i = 0; i < 6; ++i) {
            int gw = wv * 6 + i;
            gl16(W2d + (size_t)(gw * 64 + ln) * 8, w_sb + gw * 512);
        }
        if (t > 0) {
            if (tid == 0) {
                while (__hip_atomic_load(&flags[bt * 128 + t], __ATOMIC_RELAXED,
                                         __HIP_MEMORY_SCOPE_AGENT) < 16)
                    __builtin_amdgcn_s_sleep(1);
            }
        }
        __syncthreads();   // flag visible; xa/w0 staged

        // issue act interval 0 (coherent)
        #pragma unroll
        for (int i = 0; i < 2; ++i) {
            int ga = wv * 2 + i;
            gl16c(cur + ((size_t)ga * 1024 + b0 + ln) * 8, a_sb0 + ga * 512);
        }
        // x-chunk MFMA: initialize accumulators (hides part of a0 latency)
        f4 acc[2][3];
        {
            bf8 wxg[3];
            #pragma unroll
            for (int g = 0; g < 3; ++g)
                wxg[g] = *(const bf8*)&wx_s[(lg * 192 + g * 64 + coln) * 8];
            #pragma unroll
            for (int mf = 0; mf < 2; ++mf) {
                bf8 xa = *(const bf8*)&xa_s[(rbase + mf * 16 + lr) * 32 + lg * 8];
                #pragma unroll
                for (int g = 0; g < 3; ++g)
                    acc[mf][g] = __builtin_amdgcn_mfma_f32_16x16x32_bf16(
                        xa, wxg[g], fz, 0, 0, 0);
            }
        }
        f4 jacc[2] = {fz, fz};
        __syncthreads();   // a0 drained

        // ---- 8 intervals of K=128, double-buffered ----
        int buf = 0;
        for (int iv = 0; iv < NIV; ++iv) {
            unsigned short* a_cur = buf ? a_sb1 : a_sb0;
            if (iv < NIV - 1) {
                unsigned short* a_nxt = buf ? a_sb0 : a_sb1;
                #pragma unroll
                for (int i = 0; i < 2; ++i) {   // acts first (longer latency)
                    int ga = wv * 2 + i;
                    gl16c(cur + ((size_t)((iv + 1) * 16 + ga) * 1024 + b0 + ln) * 8,
                          a_nxt + ga * 512);
                }
                const unsigned short* wsrc = W2d + (size_t)(iv + 1) * 24576;
                unsigned short* w_nxt = w_sb + (buf ^ 1) * 24576;
                #pragma unroll
                for (int i = 0; i < 6; ++i) {
                    int gw = wv * 6 + i;
                    gl16(wsrc + (size_t)(gw * 64 + ln) * 8, w_nxt + gw * 512);
                }
            }
            const unsigned short* w_cur = w_sb + buf * 24576;
            #pragma unroll
            for (int ks = 0; ks < 4; ++ks) {
                int kg = ks * 4 + lg;
                bf8 bwg[3];
                #pragma unroll
                for (int g = 0; g < 3; ++g)
                    bwg[g] = *(const bf8*)&w_cur[(kg * 192 + g * 64 + coln) * 8];
                #pragma unroll
                for (int mf = 0; mf < 2; ++mf) {
                    bf8 af = *(const bf8*)&a_cur[kg * 512 + (rbase + mf * 16 + lr) * 8];
                    #pragma unroll
                    for (int g = 0; g < 3; ++g)
                        acc[mf][g] = __builtin_amdgcn_mfma_f32_16x16x32_bf16(
                            af, bwg[g], acc[mf][g], 0, 0, 0);
                }
            }
            if (iv == jiv) {   // j = h_d @ W_j[d]
                #pragma unroll
                for (int ks2 = 0; ks2 < 2; ++ks2) {
                    bf8 bw = *(const bf8*)&wj_s[((ks2 * 4 + lg) * 64 + coln) * 8];
                    #pragma unroll
                    for (int mf = 0; mf < 2; ++mf) {
                        bf8 ah = *(const bf8*)&a_cur[(jgb + ks2 * 4 + lg) * 512
                                                     + (rbase + mf * 16 + lr) * 8];
                        jacc[mf] = __builtin_amdgcn_mfma_f32_16x16x32_bf16(
                            ah, bw, jacc[mf], 0, 0, 0);
                    }
                }
            }
            __syncthreads();
            buf ^= 1;
        }

        // ---- gates + c/h update ----
        float hn_r[2][4];
        #pragma unroll
        for (int mf = 0; mf < 2; ++mf) {
            #pragma unroll
            for (int r = 0; r < 4; ++r) {
                int row = rbase + mf * 16 + lg * 4 + r;
                float jr  = tanhf_fast(jacc[mf][r] + xd_s[row] * uc + bc);
                float iv_ = sigmoidf_fast(acc[mf][0][r] + bi_c);
                float fv  = sigmoidf_fast(acc[mf][1][r] + bf_c);
                float ov  = sigmoidf_fast(acc[mf][2][r] + bo_c);
                float cn  = c_r[mf][r] * fv + iv_ * jr;
                c_r[mf][r] = cn;
                float hn = ov * tanhf_fast(cn);
                hn_r[mf][r] = hn;
                hn_s[row][coln] = hn;
            }
        }
        __syncthreads();

        // ---- publish h_{t+1} via LLC stores; post flag ----
        if (t < T_ - 1) {
            __align__(16) unsigned short pk[8];
            #pragma unroll
            for (int e = 0; e < 8; ++e) pk[e] = f2bf(hn_s[ln][wv * 8 + e]);
            st16c(nxt + ((size_t)(d * 8 + wv) * 1024 + b0 + ln) * 8,
                  *(const u32x4*)pk);
            drain_vmem();            // stores reached the LLC
            __syncthreads();         // all waves drained
            if (tid == 0)
                atomicAdd(&flags[bt * 128 + (t + 1)], 1);
        }

        // ---- online alpha accumulation ----
        {
            int br_ = tid >> 3, q = tid & 7;
            float s = 0.0f;
            #pragma unroll
            for (int i2 = 0; i2 < 8; ++i2)
                s += hn_s[br_][q * 8 + i2] * fa_s[q * 8 + i2];
            s += __shfl_xor(s, 1);
            s += __shfl_xor(s, 2);
            s += __shfl_xor(s, 4);
            float e = __expf(tanhf_fast(s + fanb));
            if (q == 0) { e_s[br_] = e; se_r += e; }
        }
        __syncthreads();
        #pragma unroll
        for (int mf = 0; mf < 2; ++mf)
            #pragma unroll
            for (int r = 0; r < 4; ++r)
                seh_r[mf][r] += e_s[rbase + mf * 16 + lg * 4 + r] * hn_r[mf][r];
    }

    // ---- final writes: hT (t=127 h), Se, Seh ----
    {
        int br_ = tid >> 3, q = tid & 7;
        #pragma unroll
        for (int i2 = 0; i2 < 2; ++i2) {
            float4 v;
            v.x = hn_s[br_][q * 8 + i2 * 4 + 0];
            v.y = hn_s[br_][q * 8 + i2 * 4 + 1];
            v.z = hn_s[br_][q * 8 + i2 * 4 + 2];
            v.w = hn_s[br_][q * 8 + i2 * 4 + 3];
            *(float4*)&hT[(size_t)(b0 + br_) * DN_ + d * 64 + q * 8 + i2 * 4] = v;
        }
        if (q == 0) Se[(size_t)(b0 + br_) * D_ + d] = se_r;
    }
    #pragma unroll
    for (int mf = 0; mf < 2; ++mf)
        #pragma unroll
        for (int r = 0; r < 4; ++r) {
            int row = rbase + mf * 16 + lg * 4 + r;
            Seh[((size_t)(b0 + row) * D_ + d) * 64 + coln] = seh_r[mf][r];
        }
}

// ---- epilogue ----
__global__ __launch_bounds__(64)
void final_kernel(const float* __restrict__ hT,
                  const float* __restrict__ Se, const float* __restrict__ Seh,
                  const float* __restrict__ F_bw, const float* __restrict__ F_bb,
                  const float* __restrict__ Phi_w, const float* __restrict__ Phi_b,
                  float* __restrict__ out)
{
    int b = blockIdx.x;
    int tid = threadIdx.x;
    int d = tid >> 2, q = tid & 3;
    float se_inv = 1.0f / Se[(size_t)b * D_ + d];
    float mu = 0.0f, be = 0.0f;
    #pragma unroll
    for (int i = 0; i < 32; ++i) {
        int k = q * 32 + i;
        float hg = (k < 64) ? Seh[((size_t)b * D_ + d) * 64 + k] * se_inv
                            : hT[(size_t)b * DN_ + d * 64 + (k - 64)];
        mu += hg * Phi_w[k];
        be += hg * F_bw[k];
    }
    mu += __shfl_xor(mu, 1); mu += __shfl_xor(mu, 2);
    be += __shfl_xor(be, 1); be += __shfl_xor(be, 2);
    float mud = mu + Phi_b[0];
    float br  = __expf(tanhf_fast(be + F_bb[0]));
    float num = br * mud, den = br;
    #pragma unroll
    for (int off = 4; off < 64; off <<= 1) {
        num += __shfl_xor(num, off);
        den += __shfl_xor(den, off);
    }
    if (tid == 0) out[b] = num / den;
}

extern "C" void kernel_launch(void* const* d_in, const int* in_sizes, int n_in,
                              void* d_out, int out_size, void* d_ws, size_t ws_size,
                              hipStream_t stream)
{
    (void)in_sizes; (void)n_in; (void)out_size; (void)ws_size;
    const float* x     = (const float*)d_in[0];
    const float* U_j   = (const float*)d_in[1];
    const float* W_j   = (const float*)d_in[2];
    const float* b_j   = (const float*)d_in[3];
    const float* Wi_w  = (const float*)d_in[4];
    const float* Wi_b  = (const float*)d_in[5];
    const float* Wf_w  = (const float*)d_in[6];
    const float* Wf_b  = (const float*)d_in[7];
    const float* Wo_w  = (const float*)d_in[8];
    const float* Wo_b  = (const float*)d_in[9];
    const float* F_an  = (const float*)d_in[10];
    const float* F_anb = (const float*)d_in[11];
    const float* F_bw  = (const float*)d_in[12];
    const float* F_bb  = (const float*)d_in[13];
    const float* Phi_w = (const float*)d_in[14];
    const float* Phi_b = (const float*)d_in[15];
    float* out = (float*)d_out;

    char* ws = (char*)d_ws;
    unsigned short* inp0 = (unsigned short*)(ws + OFF_INP0);
    unsigned short* inp1 = (unsigned short*)(ws + OFF_INP1);
    int*   flags = (int*)(ws + OFF_FLAGS);
    float* Seh   = (float*)(ws + OFF_SEH);
    float* Se    = (float*)(ws + OFF_SE);
    float* hT    = (float*)(ws + OFF_HT);
    unsigned short* W2  = (unsigned short*)(ws + OFF_W2);
    unsigned short* Wj2 = (unsigned short*)(ws + OFF_WJ2);
    unsigned short* Wx2 = (unsigned short*)(ws + OFF_WX2);

    // zero only inp0 (t=0 h must be 0) and flags; inp1 is written at t=0
    // publish before any t=1 read.
    (void)hipMemsetAsync(ws + OFF_INP0, 0, INPBUF, stream);
    (void)hipMemsetAsync(ws + OFF_FLAGS, 0, FLAGS_BYTES, stream);
    prep_w2<<<dim3(12288), dim3(256), 0, stream>>>(Wi_w, Wf_w, Wo_w, W2);
    prep_misc<<<dim3(640), dim3(256), 0, stream>>>(W_j, Wi_w, Wf_w, Wo_w, Wj2, Wx2);

    // 1D grid, XCD-aware decode inside the kernel; 1 block/CU (153KB LDS)
    scan_kernel<<<dim3(256), dim3(512), 0, stream>>>(
        x, U_j, b_j, Wi_b, Wf_b, Wo_b, F_an, F_anb,
        W2, Wj2, Wx2, inp0, inp1, flags, Seh, Se, hT);

    final_kernel<<<dim3(B_), dim3(64), 0, stream>>>(hT, Se, Seh, F_bw, F_bb,
                                                    Phi_w, Phi_b, out);
}